// Round 9
// baseline (143.808 us; speedup 1.0000x reference)
//
#include <hip/hip_runtime.h>
#include <hip/hip_bf16.h>

#define NTOK 8192
#define DDIM 512
#define HDIM 1024
#define NEXP 8
#define TOPK 2

typedef __attribute__((ext_vector_type(8))) short short8;
typedef __attribute__((ext_vector_type(4))) float f32x4;

// fp32 -> bf16 round-to-nearest-even (finite inputs)
__device__ __forceinline__ short f2bf(float f) {
  union { float f; unsigned u; } v; v.f = f;
  unsigned r = v.u + 0x7fffu + ((v.u >> 16) & 1u);
  return (short)(r >> 16);
}
__device__ __forceinline__ float bf2f(short s) {
  union { unsigned u; float f; } v; v.u = ((unsigned)(unsigned short)s) << 16;
  return v.f;
}

__device__ __forceinline__ void async_lds16(const void* g, void* l) {
  __builtin_amdgcn_global_load_lds(
      (const __attribute__((address_space(1))) unsigned int*)g,
      (__attribute__((address_space(3))) unsigned int*)l,
      16, 0, 0);
}

// fast GELU: v * sigmoid(2u)  (~8 VALU ops); |diff vs erf GELU| < ~1e-3, thr 0.14
__device__ __forceinline__ float gelu_f(float v) {
  float u2 = v * v;
  float z = v * (-1.5957691216f - 0.0713548163f * u2);  // -2u
  float t = __expf(z);
  return v * __builtin_amdgcn_rcpf(1.f + t);
}

// ---------------- transpose fp32 [M][R][C] -> bf16 [M][C][R] ----------------
__global__ __launch_bounds__(256) void transpose_bf16_kernel(const float* __restrict__ src,
                                                             short* __restrict__ dst,
                                                             int R, int C) {
  __shared__ float tile[32][33];
  int m = blockIdx.z;
  int c0 = blockIdx.x * 32, r0 = blockIdx.y * 32;
  const float* s = src + (size_t)m * R * C;
  short* d = dst + (size_t)m * R * C;
  int tx = threadIdx.x, ty = threadIdx.y;
#pragma unroll
  for (int i = 0; i < 4; ++i)
    tile[ty + i * 8][tx] = s[(size_t)(r0 + ty + i * 8) * C + c0 + tx];
  __syncthreads();
#pragma unroll
  for (int i = 0; i < 4; ++i)
    d[(size_t)(c0 + ty + i * 8) * R + r0 + tx] = f2bf(tile[tx][ty + i * 8]);
}

// ---------------- router: fp32 logits, top-2, softmax; converts x->bf16; zeroes ctrl ----------------
__global__ __launch_bounds__(256) void router_compute(
    const float* __restrict__ x, const float* __restrict__ wg,
    float* __restrict__ out_logits, float* __restrict__ out_idx,
    float* __restrict__ out_w, short* __restrict__ xb, int* __restrict__ counts) {
  if (blockIdx.x == 0 && threadIdx.x < NEXP) counts[threadIdx.x] = 0;  // ordered before build_lists
  int wave = threadIdx.x >> 6;
  int lane = threadIdx.x & 63;
  int n = blockIdx.x * 4 + wave;

  const float* xrow = x + (size_t)n * DDIM;
  const float4* xv = (const float4*)xrow;
  float4 xa = xv[lane * 2], xbv = xv[lane * 2 + 1];
  float xs[8] = {xa.x, xa.y, xa.z, xa.w, xbv.x, xbv.y, xbv.z, xbv.w};

  short8 xc;
#pragma unroll
  for (int j = 0; j < 8; ++j) xc[j] = f2bf(xs[j]);
  *(short8*)(xb + (size_t)n * DDIM + lane * 8) = xc;

  float acc[8] = {0, 0, 0, 0, 0, 0, 0, 0};
#pragma unroll
  for (int j = 0; j < 8; ++j) {
    const float4* wr = (const float4*)(wg + (size_t)(lane * 8 + j) * NEXP);
    float4 w0 = wr[0], w1 = wr[1];
    float xj = xs[j];
    acc[0] += xj * w0.x; acc[1] += xj * w0.y; acc[2] += xj * w0.z; acc[3] += xj * w0.w;
    acc[4] += xj * w1.x; acc[5] += xj * w1.y; acc[6] += xj * w1.z; acc[7] += xj * w1.w;
  }
#pragma unroll
  for (int m = 32; m >= 1; m >>= 1) {
#pragma unroll
    for (int e = 0; e < 8; ++e) acc[e] += __shfl_xor(acc[e], m);
  }
  if (lane == 0) {
#pragma unroll
    for (int e = 0; e < 8; ++e) out_logits[(size_t)n * NEXP + e] = acc[e];
    int i1 = 0; float v1 = acc[0];
#pragma unroll
    for (int e = 1; e < 8; ++e) if (acc[e] > v1) { v1 = acc[e]; i1 = e; }
    int i2 = -1; float v2 = -3.4e38f;
#pragma unroll
    for (int e = 0; e < 8; ++e) if (e != i1 && acc[e] > v2) { v2 = acc[e]; i2 = e; }
    float ex = expf(v2 - v1);
    float s = 1.f / (1.f + ex);
    out_idx[n * 2] = (float)i1; out_idx[n * 2 + 1] = (float)i2;
    out_w[n * 2] = s; out_w[n * 2 + 1] = ex * s;
  }
}

// ---------------- build per-expert token lists (wave-aggregated atomics) ----------------
__global__ __launch_bounds__(512) void build_lists(
    const float* __restrict__ idxf,
    int* __restrict__ counts, int* __restrict__ tok_list, int* __restrict__ slot_enc) {
  int t = blockIdx.x * 512 + threadIdx.x;
  int lane = threadIdx.x & 63;
  float2 iv = *(const float2*)(idxf + (size_t)t * 2);
  int es[2] = {(int)iv.x, (int)iv.y};
#pragma unroll
  for (int s = 0; s < 2; ++s) {
    int e = es[s];
#pragma unroll
    for (int ex = 0; ex < NEXP; ++ex) {
      unsigned long long m = __ballot(e == ex);
      if (e == ex) {
        int leader = __ffsll(m) - 1;
        int base = 0;
        if (lane == leader) base = atomicAdd(&counts[ex], __popcll(m));
        base = __shfl(base, leader);
        int rank = __popcll(m & ((1ull << lane) - 1ull));
        tok_list[ex * NTOK + base + rank] = t;
        slot_enc[t * 2 + s] = (ex << 16) | (base + rank);
      }
    }
  }
}

// =====================================================================================
// GEMM1: 256x256 tile, 8 waves (128x64 each), BK=32, 2 LDS bufs (64KB), depth-1 prefetch,
// R7-validated sync skeleton; pre-swizzled source + swizzled ds_read; XCD = expert.
// =====================================================================================
__global__ __launch_bounds__(512, 2) void expert_gemm1(
    const short* __restrict__ xb, const short* __restrict__ w1t,
    const float* __restrict__ b1, short* __restrict__ hbuf,
    const int* __restrict__ ctrl, const int* __restrict__ tok_list) {
  int raw = blockIdx.x;
  int bid = (raw & 7) * 64 + (raw >> 3);  // 512 blocks: XCD x owns expert x
  int e = bid >> 6;
  int rem = bid & 63;
  int mt = rem >> 2;       // 0..15 (covers ce <= 4096)
  int nt = rem & 3;        // H/256
  int ce = ctrl[e];
  int m0 = mt * 256;
  if (m0 >= ce) return;
  int offe = 0;
#pragma unroll
  for (int i = 0; i < NEXP; ++i) offe += (i < e) ? ctrl[i] : 0;

  __shared__ char smem[65536];  // 2 bufs x (A 16KB | B 16KB); epilogue reuses 34.8KB

  int tid = threadIdx.x;
  int wave = tid >> 6;
  int lane = tid & 63;

  // ---- staging addresses (per lane, hoisted): wave stages A rows [w*32,w*32+32), same for B
  int laneRow = lane >> 2;          // 0..15
  int chunk = lane & 3;             // 16B chunk within 64B row
  int r0 = wave * 32 + laneRow;     // LDS row, instr 0
  int r1 = r0 + 16;                 // instr 1
  int swz0 = (chunk ^ ((r0 >> 1) & 3)) * 8;  // shorts; source pre-swizzle involution
  int swz1 = (chunk ^ ((r1 >> 1) & 3)) * 8;
  int ga0 = m0 + r0; if (ga0 >= ce) ga0 = ce - 1;
  int ga1 = m0 + r1; if (ga1 >= ce) ga1 = ce - 1;
  const short* a0 = xb + (size_t)tok_list[e * NTOK + ga0] * DDIM + swz0;
  const short* a1 = xb + (size_t)tok_list[e * NTOK + ga1] * DDIM + swz1;
  const short* b0 = w1t + ((size_t)e * HDIM + nt * 256 + r0) * DDIM + swz0;
  const short* b1p = w1t + ((size_t)e * HDIM + nt * 256 + r1) * DDIM + swz1;

  f32x4 acc[8][4];
#pragma unroll
  for (int i = 0; i < 8; ++i)
#pragma unroll
    for (int j = 0; j < 4; ++j) acc[i][j] = (f32x4){0.f, 0.f, 0.f, 0.f};

  int wm = (wave >> 2) * 128;   // 2 M-halves
  int wn = (wave & 3) * 64;     // 4 N-quarters
  int lr = lane & 15;
  int kswz = ((lane >> 4) * 8) ^ (((lr >> 1) & 3) << 3);

#define STAGE1(t) do {                                                   \
    int _k = (t) * 32;                                                   \
    char* _b = smem + (((t) & 1) << 15);                                 \
    async_lds16(a0 + _k, _b + (wave * 32) * 64);                         \
    async_lds16(a1 + _k, _b + (wave * 32 + 16) * 64);                    \
    async_lds16(b0 + _k, _b + 16384 + (wave * 32) * 64);                 \
    async_lds16(b1p + _k, _b + 16384 + (wave * 32 + 16) * 64);           \
  } while (0)

  STAGE1(0);
#pragma unroll
  for (int t = 0; t < 16; ++t) {
    // tile t's DMA (all waves) landed once every wave passes this barrier
    asm volatile("s_waitcnt vmcnt(0)\n\ts_barrier" ::: "memory");
    __builtin_amdgcn_sched_barrier(0);
    // buf[(t+1)&1] was read at t-1; all waves drained lgkmcnt(0) there before this barrier
    if (t + 1 < 16) STAGE1(t + 1);
    const short* As = (const short*)(smem + ((t & 1) << 15));
    const short* Bs = As + 8192;
    short8 a[8], b[4];
#pragma unroll
    for (int i = 0; i < 8; ++i) a[i] = *(const short8*)&As[(wm + i * 16 + lr) * 32 + kswz];
#pragma unroll
    for (int j = 0; j < 4; ++j) b[j] = *(const short8*)&Bs[(wn + j * 16 + lr) * 32 + kswz];
    asm volatile("s_waitcnt lgkmcnt(0)" ::: "memory");  // reads SERVICED before next barrier
    __builtin_amdgcn_sched_barrier(0);                  // keep MFMA below the wait
    __builtin_amdgcn_s_setprio(1);
#pragma unroll
    for (int i = 0; i < 8; ++i)
#pragma unroll
      for (int j = 0; j < 4; ++j)
        acc[i][j] = __builtin_amdgcn_mfma_f32_16x16x32_bf16(a[i], b[j], acc[i][j], 0, 0, 0);
    __builtin_amdgcn_s_setprio(0);
  }
#undef STAGE1
  __syncthreads();  // all K-loop reads done before epilogue reuses smem

  // ---- epilogue: 4 passes of 32 rows; GELU -> bf16 -> LDS -> coalesced short8 stores
  int colb = nt * 256 + wn;
  float bb[4];
#pragma unroll
  for (int j = 0; j < 4; ++j) bb[j] = b1[e * HDIM + colb + j * 16 + lr];
  short* ep = (short*)smem + wave * 2176;  // 32 rows x 68 shorts per wave
#pragma unroll
  for (int p = 0; p < 4; ++p) {
#pragma unroll
    for (int ii = 0; ii < 2; ++ii) {
      int i = p * 2 + ii;
#pragma unroll
      for (int j = 0; j < 4; ++j) {
#pragma unroll
        for (int q = 0; q < 4; ++q) {
          int rl = ii * 16 + (lane >> 4) * 4 + q;
          ep[rl * 68 + j * 16 + lr] = f2bf(gelu_f(acc[i][j][q] + bb[j]));
        }
      }
    }
    __syncthreads();
#pragma unroll
    for (int s = 0; s < 4; ++s) {
      int idx = s * 64 + lane;
      int rl = idx >> 3;
      int c8 = (idx & 7) * 8;
      int gidx = m0 + wm + p * 32 + rl;
      if (gidx < ce) {
        *(short8*)&hbuf[(size_t)(offe + gidx) * HDIM + colb + c8] = *(short8*)&ep[rl * 68 + c8];
      }
    }
    __syncthreads();
  }
}

// =====================================================================================
// GEMM2: same structure; A = hbuf (contiguous slots), K=1024, N=512, writes ybuf (+bias)
// =====================================================================================
__global__ __launch_bounds__(512, 2) void expert_gemm2(
    const short* __restrict__ hbuf, const short* __restrict__ w2t,
    const float* __restrict__ b2, short* __restrict__ ybuf,
    const int* __restrict__ ctrl) {
  int raw = blockIdx.x;
  int bid = (raw & 7) * 32 + (raw >> 3);  // 256 blocks: XCD x owns expert x
  int e = bid >> 5;
  int rem = bid & 31;
  int mt = rem >> 1;       // 0..15
  int nt = rem & 1;        // D/256
  int ce = ctrl[e];
  int m0 = mt * 256;
  if (m0 >= ce) return;
  int offe = 0;
#pragma unroll
  for (int i = 0; i < NEXP; ++i) offe += (i < e) ? ctrl[i] : 0;

  __shared__ char smem[65536];

  int tid = threadIdx.x;
  int wave = tid >> 6;
  int lane = tid & 63;

  int laneRow = lane >> 2;
  int chunk = lane & 3;
  int r0 = wave * 32 + laneRow;
  int r1 = r0 + 16;
  int swz0 = (chunk ^ ((r0 >> 1) & 3)) * 8;
  int swz1 = (chunk ^ ((r1 >> 1) & 3)) * 8;
  int ga0 = m0 + r0; if (ga0 >= ce) ga0 = ce - 1;
  int ga1 = m0 + r1; if (ga1 >= ce) ga1 = ce - 1;
  const short* a0 = hbuf + (size_t)(offe + ga0) * HDIM + swz0;
  const short* a1 = hbuf + (size_t)(offe + ga1) * HDIM + swz1;
  const short* b0 = w2t + ((size_t)e * DDIM + nt * 256 + r0) * HDIM + swz0;
  const short* b1p = w2t + ((size_t)e * DDIM + nt * 256 + r1) * HDIM + swz1;

  f32x4 acc[8][4];
#pragma unroll
  for (int i = 0; i < 8; ++i)
#pragma unroll
    for (int j = 0; j < 4; ++j) acc[i][j] = (f32x4){0.f, 0.f, 0.f, 0.f};

  int wm = (wave >> 2) * 128;
  int wn = (wave & 3) * 64;
  int lr = lane & 15;
  int kswz = ((lane >> 4) * 8) ^ (((lr >> 1) & 3) << 3);

#define STAGE2(t) do {                                                   \
    int _k = (t) * 32;                                                   \
    char* _b = smem + (((t) & 1) << 15);                                 \
    async_lds16(a0 + _k, _b + (wave * 32) * 64);                         \
    async_lds16(a1 + _k, _b + (wave * 32 + 16) * 64);                    \
    async_lds16(b0 + _k, _b + 16384 + (wave * 32) * 64);                 \
    async_lds16(b1p + _k, _b + 16384 + (wave * 32 + 16) * 64);           \
  } while (0)

  STAGE2(0);
#pragma unroll
  for (int t = 0; t < 32; ++t) {
    asm volatile("s_waitcnt vmcnt(0)\n\ts_barrier" ::: "memory");
    __builtin_amdgcn_sched_barrier(0);
    if (t + 1 < 32) STAGE2(t + 1);
    const short* As = (const short*)(smem + ((t & 1) << 15));
    const short* Bs = As + 8192;
    short8 a[8], b[4];
#pragma unroll
    for (int i = 0; i < 8; ++i) a[i] = *(const short8*)&As[(wm + i * 16 + lr) * 32 + kswz];
#pragma unroll
    for (int j = 0; j < 4; ++j) b[j] = *(const short8*)&Bs[(wn + j * 16 + lr) * 32 + kswz];
    asm volatile("s_waitcnt lgkmcnt(0)" ::: "memory");
    __builtin_amdgcn_sched_barrier(0);
    __builtin_amdgcn_s_setprio(1);
#pragma unroll
    for (int i = 0; i < 8; ++i)
#pragma unroll
      for (int j = 0; j < 4; ++j)
        acc[i][j] = __builtin_amdgcn_mfma_f32_16x16x32_bf16(a[i], b[j], acc[i][j], 0, 0, 0);
    __builtin_amdgcn_s_setprio(0);
  }
#undef STAGE2
  __syncthreads();

  // ---- epilogue: 4 passes; +bias -> bf16 -> LDS -> coalesced short8 stores
  int colb = nt * 256 + wn;
  float bb[4];
#pragma unroll
  for (int j = 0; j < 4; ++j) bb[j] = b2[e * DDIM + colb + j * 16 + lr];
  short* ep = (short*)smem + wave * 2176;
#pragma unroll
  for (int p = 0; p < 4; ++p) {
#pragma unroll
    for (int ii = 0; ii < 2; ++ii) {
      int i = p * 2 + ii;
#pragma unroll
      for (int j = 0; j < 4; ++j) {
#pragma unroll
        for (int q = 0; q < 4; ++q) {
          int rl = ii * 16 + (lane >> 4) * 4 + q;
          ep[rl * 68 + j * 16 + lr] = f2bf(acc[i][j][q] + bb[j]);
        }
      }
    }
    __syncthreads();
#pragma unroll
    for (int s = 0; s < 4; ++s) {
      int idx = s * 64 + lane;
      int rl = idx >> 3;
      int c8 = (idx & 7) * 8;
      int gidx = m0 + wm + p * 32 + rl;
      if (gidx < ce) {
        *(short8*)&ybuf[(size_t)(offe + gidx) * DDIM + colb + c8] = *(short8*)&ep[rl * 68 + c8];
      }
    }
    __syncthreads();
  }
}

// ---------------- combine: out[n] = w0*ybuf[slot0] + w1*ybuf[slot1] ----------------
__global__ __launch_bounds__(256) void combine_kernel(
    const short* __restrict__ ybuf, const int* __restrict__ slot_enc,
    const float* __restrict__ wf, const int* __restrict__ ctrl,
    float* __restrict__ out) {
  int wave = threadIdx.x >> 6;
  int lane = threadIdx.x & 63;
  int n = blockIdx.x * 4 + wave;
  int s0 = slot_enc[n * 2], s1 = slot_enc[n * 2 + 1];
  float w0 = wf[n * 2], w1 = wf[n * 2 + 1];
  int e0 = s0 >> 16, e1 = s1 >> 16;
  int off0 = 0, off1 = 0;
#pragma unroll
  for (int i = 0; i < NEXP; ++i) {
    int c = ctrl[i];
    off0 += (i < e0) ? c : 0;
    off1 += (i < e1) ? c : 0;
  }
  int r0 = off0 + (s0 & 0xffff);
  int r1 = off1 + (s1 & 0xffff);
  short8 a = *(const short8*)&ybuf[(size_t)r0 * DDIM + lane * 8];
  short8 b = *(const short8*)&ybuf[(size_t)r1 * DDIM + lane * 8];
  float r[8];
#pragma unroll
  for (int k = 0; k < 8; ++k) r[k] = w0 * bf2f(a[k]) + w1 * bf2f(b[k]);
  float4 o0 = {r[0], r[1], r[2], r[3]};
  float4 o1 = {r[4], r[5], r[6], r[7]};
  *(float4*)&out[(size_t)n * DDIM + lane * 8] = o0;
  *(float4*)&out[(size_t)n * DDIM + lane * 8 + 4] = o1;
}

extern "C" void kernel_launch(void* const* d_in, const int* in_sizes, int n_in,
                              void* d_out, int out_size, void* d_ws, size_t ws_size,
                              hipStream_t stream) {
  const float* x  = (const float*)d_in[0];
  const float* wg = (const float*)d_in[1];
  const float* w1 = (const float*)d_in[2];
  const float* b1 = (const float*)d_in[3];
  const float* w2 = (const float*)d_in[4];
  const float* b2 = (const float*)d_in[5];
  float* out = (float*)d_out;

  char* ws = (char*)d_ws;
  int*   ctrl = (int*)ws;                    // [0..7] counts
  int*   tok  = (int*)(ws + 1024);           // 256 KB
  int*   slot = (int*)(ws + 263168);         // 64 KB
  short* xb   = (short*)(ws + 328704);       // 8 MB
  short* w1t  = (short*)(ws + 8717312);      // 8 MB [E][H][D]
  short* w2t  = (short*)(ws + 17105920);     // 8 MB [E][D][H]
  short* hb   = (short*)(ws + 25494528);     // 32 MB
  short* yb   = (short*)(ws + 328704);       // 16 MB, ALIASES xb+w1t (dead by GEMM2)

  transpose_bf16_kernel<<<dim3(32, 16, 8), dim3(32, 8), 0, stream>>>(w1, w1t, DDIM, HDIM);
  transpose_bf16_kernel<<<dim3(16, 32, 8), dim3(32, 8), 0, stream>>>(w2, w2t, HDIM, DDIM);

  float* out_logits = out + (size_t)NTOK * DDIM;
  float* out_idx = out_logits + (size_t)NTOK * NEXP;
  float* out_w = out_idx + (size_t)NTOK * TOPK;
  router_compute<<<2048, 256, 0, stream>>>(x, wg, out_logits, out_idx, out_w, xb, ctrl);
  build_lists<<<16, 512, 0, stream>>>(out_idx, ctrl, tok, slot);

  expert_gemm1<<<512, 512, 0, stream>>>(xb, w1t, b1, hb, ctrl, tok);
  expert_gemm2<<<256, 512, 0, stream>>>(hb, w2t, b2, yb, ctrl);
  combine_kernel<<<2048, 256, 0, stream>>>(yb, slot, out_w, ctrl, out);
}

// Round 10
// 128.085 us; speedup vs baseline: 1.1227x; 1.1227x over previous
//
#include <hip/hip_runtime.h>
#include <hip/hip_bf16.h>

#define NTOK 8192
#define DDIM 512
#define HDIM 1024
#define NEXP 8
#define TOPK 2

typedef __attribute__((ext_vector_type(8))) short short8;
typedef __attribute__((ext_vector_type(4))) float f32x4;

// fp32 -> bf16 round-to-nearest-even (finite inputs)
__device__ __forceinline__ short f2bf(float f) {
  union { float f; unsigned u; } v; v.f = f;
  unsigned r = v.u + 0x7fffu + ((v.u >> 16) & 1u);
  return (short)(r >> 16);
}
__device__ __forceinline__ float bf2f(short s) {
  union { unsigned u; float f; } v; v.u = ((unsigned)(unsigned short)s) << 16;
  return v.f;
}

__device__ __forceinline__ void async_lds16(const void* g, void* l) {
  __builtin_amdgcn_global_load_lds(
      (const __attribute__((address_space(1))) unsigned int*)g,
      (__attribute__((address_space(3))) unsigned int*)l,
      16, 0, 0);
}

// fast GELU: v * sigmoid(2u)  (~8 VALU ops); |diff vs erf GELU| < ~1e-3, thr 0.14
__device__ __forceinline__ float gelu_f(float v) {
  float u2 = v * v;
  float z = v * (-1.5957691216f - 0.0713548163f * u2);  // -2u
  float t = __expf(z);
  return v * __builtin_amdgcn_rcpf(1.f + t);
}

// ---------------- transpose fp32 [M][R][C] -> bf16 [M][C][R] ----------------
__global__ __launch_bounds__(256) void transpose_bf16_kernel(const float* __restrict__ src,
                                                             short* __restrict__ dst,
                                                             int R, int C) {
  __shared__ float tile[32][33];
  int m = blockIdx.z;
  int c0 = blockIdx.x * 32, r0 = blockIdx.y * 32;
  const float* s = src + (size_t)m * R * C;
  short* d = dst + (size_t)m * R * C;
  int tx = threadIdx.x, ty = threadIdx.y;
#pragma unroll
  for (int i = 0; i < 4; ++i)
    tile[ty + i * 8][tx] = s[(size_t)(r0 + ty + i * 8) * C + c0 + tx];
  __syncthreads();
#pragma unroll
  for (int i = 0; i < 4; ++i)
    d[(size_t)(c0 + ty + i * 8) * R + r0 + tx] = f2bf(tile[tx][ty + i * 8]);
}

// ---------------- router: fp32 logits, top-2, softmax; converts x->bf16; zeroes ctrl ----------------
__global__ __launch_bounds__(256) void router_compute(
    const float* __restrict__ x, const float* __restrict__ wg,
    float* __restrict__ out_logits, float* __restrict__ out_idx,
    float* __restrict__ out_w, short* __restrict__ xb, int* __restrict__ counts) {
  if (blockIdx.x == 0 && threadIdx.x < NEXP) counts[threadIdx.x] = 0;  // ordered before build_lists
  int wave = threadIdx.x >> 6;
  int lane = threadIdx.x & 63;
  int n = blockIdx.x * 4 + wave;

  const float* xrow = x + (size_t)n * DDIM;
  const float4* xv = (const float4*)xrow;
  float4 xa = xv[lane * 2], xbv = xv[lane * 2 + 1];
  float xs[8] = {xa.x, xa.y, xa.z, xa.w, xbv.x, xbv.y, xbv.z, xbv.w};

  short8 xc;
#pragma unroll
  for (int j = 0; j < 8; ++j) xc[j] = f2bf(xs[j]);
  *(short8*)(xb + (size_t)n * DDIM + lane * 8) = xc;

  float acc[8] = {0, 0, 0, 0, 0, 0, 0, 0};
#pragma unroll
  for (int j = 0; j < 8; ++j) {
    const float4* wr = (const float4*)(wg + (size_t)(lane * 8 + j) * NEXP);
    float4 w0 = wr[0], w1 = wr[1];
    float xj = xs[j];
    acc[0] += xj * w0.x; acc[1] += xj * w0.y; acc[2] += xj * w0.z; acc[3] += xj * w0.w;
    acc[4] += xj * w1.x; acc[5] += xj * w1.y; acc[6] += xj * w1.z; acc[7] += xj * w1.w;
  }
#pragma unroll
  for (int m = 32; m >= 1; m >>= 1) {
#pragma unroll
    for (int e = 0; e < 8; ++e) acc[e] += __shfl_xor(acc[e], m);
  }
  if (lane == 0) {
#pragma unroll
    for (int e = 0; e < 8; ++e) out_logits[(size_t)n * NEXP + e] = acc[e];
    int i1 = 0; float v1 = acc[0];
#pragma unroll
    for (int e = 1; e < 8; ++e) if (acc[e] > v1) { v1 = acc[e]; i1 = e; }
    int i2 = -1; float v2 = -3.4e38f;
#pragma unroll
    for (int e = 0; e < 8; ++e) if (e != i1 && acc[e] > v2) { v2 = acc[e]; i2 = e; }
    float ex = expf(v2 - v1);
    float s = 1.f / (1.f + ex);
    out_idx[n * 2] = (float)i1; out_idx[n * 2 + 1] = (float)i2;
    out_w[n * 2] = s; out_w[n * 2 + 1] = ex * s;
  }
}

// ---------------- build per-expert token lists (wave-aggregated atomics) ----------------
__global__ __launch_bounds__(512) void build_lists(
    const float* __restrict__ idxf,
    int* __restrict__ counts, int* __restrict__ tok_list, int* __restrict__ slot_enc) {
  int t = blockIdx.x * 512 + threadIdx.x;
  int lane = threadIdx.x & 63;
  float2 iv = *(const float2*)(idxf + (size_t)t * 2);
  int es[2] = {(int)iv.x, (int)iv.y};
#pragma unroll
  for (int s = 0; s < 2; ++s) {
    int e = es[s];
#pragma unroll
    for (int ex = 0; ex < NEXP; ++ex) {
      unsigned long long m = __ballot(e == ex);
      if (e == ex) {
        int leader = __ffsll(m) - 1;
        int base = 0;
        if (lane == leader) base = atomicAdd(&counts[ex], __popcll(m));
        base = __shfl(base, leader);
        int rank = __popcll(m & ((1ull << lane) - 1ull));
        tok_list[ex * NTOK + base + rank] = t;
        slot_enc[t * 2 + s] = (ex << 16) | (base + rank);
      }
    }
  }
}

// ---------------- GEMM1: h = GELU(gather(x) @ W1[e] + b1[e]) -> bf16 hbuf ----------------
// depth-2 counted-vmcnt pipeline (3 LDS bufs); trailing lgkmcnt(0) (invariant: reads
// serviced before next barrier) lets the compiler interleave ds_read with MFMA;
// pre-swizzled source + swizzled ds_read (0 bank conflicts); XCD = expert.
__global__ __launch_bounds__(256) void expert_gemm1(
    const short* __restrict__ xb, const short* __restrict__ w1t,
    const float* __restrict__ b1, short* __restrict__ hbuf,
    const int* __restrict__ ctrl, const int* __restrict__ tok_list) {
  int raw = blockIdx.x;
  int bid = (raw & 7) * 512 + (raw >> 3);  // bijective: XCD x owns expert x
  int e = bid >> 9;
  int rem = bid & 511;
  int mt = rem >> 3;
  int nt = rem & 7;
  int ce = ctrl[e];
  int m0 = mt * 128;
  if (m0 >= ce) return;
  int offe = 0;
#pragma unroll
  for (int i = 0; i < NEXP; ++i) offe += (i < e) ? ctrl[i] : 0;

  // LDS: 3 pipeline buffers x 16KB (As 8K | Bs 8K each); epilogue reuses [0,34816)
  __shared__ char smem[49152];

  int tid = threadIdx.x;
  int wave = tid >> 6;
  int lane = tid & 63;

  int sr = tid >> 2;
  // Pre-swizzled source: lane writes LDS chunk (sr, tid&3); fetch the global chunk
  // that belongs there under involution chunk^=((row>>1)&3)
  int kc = (((tid & 3) ^ ((sr >> 1) & 3)) * 8);
  int ia = m0 + sr;      if (ia >= ce) ia = ce - 1;
  int ib = m0 + sr + 64; if (ib >= ce) ib = ce - 1;
  const short* gA0 = xb + (size_t)tok_list[e * NTOK + ia] * DDIM + kc;
  const short* gA1 = xb + (size_t)tok_list[e * NTOK + ib] * DDIM + kc;
  const short* gB0 = w1t + ((size_t)e * HDIM + nt * 128 + sr) * DDIM + kc;
  const short* gB1 = gB0 + (size_t)64 * DDIM;

  f32x4 acc[4][4];
#pragma unroll
  for (int i = 0; i < 4; ++i)
#pragma unroll
    for (int j = 0; j < 4; ++j) acc[i][j] = (f32x4){0.f, 0.f, 0.f, 0.f};

  int wm = (wave >> 1) * 64;
  int wn = (wave & 1) * 64;
  int lr = lane & 15;
  // swizzled read column (shorts): same involution
  int kswz = ((lane >> 4) * 8) ^ (((lr >> 1) & 3) << 3);

#define STAGE1(t) do {                                                  \
    int _k = (t) * 32;                                                  \
    char* _lA = smem + ((t) % 3) * 16384 + wave * 1024;                 \
    char* _lB = _lA + 8192;                                             \
    async_lds16(gA0 + _k, _lA); async_lds16(gA1 + _k, _lA + 4096);      \
    async_lds16(gB0 + _k, _lB); async_lds16(gB1 + _k, _lB + 4096);      \
  } while (0)

  STAGE1(0);
  STAGE1(1);
#pragma unroll
  for (int t = 0; t < 16; ++t) {
    // Tile t's DMA (all waves) landed once every wave passes this barrier.
    if (t < 15) asm volatile("s_waitcnt vmcnt(4)\n\ts_barrier" ::: "memory");
    else        asm volatile("s_waitcnt vmcnt(0)\n\ts_barrier" ::: "memory");
    // buf[(t+2)%3]==buf[(t-1)%3] safe: all waves drained lgkmcnt(0) in iter t-1
    // (trailing wait below) before arriving at the barrier above.
    if (t + 2 < 16) STAGE1(t + 2);
    const short* As = (const short*)(smem + (t % 3) * 16384);
    const short* Bs = As + 4096;
    short8 a[4], b[4];
#pragma unroll
    for (int i = 0; i < 4; ++i) a[i] = *(const short8*)&As[(wm + i * 16 + lr) * 32 + kswz];
#pragma unroll
    for (int j = 0; j < 4; ++j) b[j] = *(const short8*)&Bs[(wn + j * 16 + lr) * 32 + kswz];
    // No manual drain here: compiler emits counted lgkmcnt before each first use,
    // interleaving ds_read latency with MFMA issue.
    __builtin_amdgcn_s_setprio(1);
#pragma unroll
    for (int i = 0; i < 4; ++i)
#pragma unroll
      for (int j = 0; j < 4; ++j)
        acc[i][j] = __builtin_amdgcn_mfma_f32_16x16x32_bf16(a[i], b[j], acc[i][j], 0, 0, 0);
    __builtin_amdgcn_s_setprio(0);
    // Invariant: this wave's ds_reads are SERVICED before it reaches the next barrier.
    // (ds_reads cannot sink below this memory-clobber asm.)
    asm volatile("s_waitcnt lgkmcnt(0)" ::: "memory");
  }
#undef STAGE1
  __syncthreads();  // all K-loop reads done before epilogue reuses smem

  // ---- LDS-staged epilogue: GELU -> bf16 -> per-wave 64x68 tile -> coalesced short8 stores
  short* ep = (short*)(smem + wave * 8704);
  int colb = nt * 128 + wn;
#pragma unroll
  for (int j = 0; j < 4; ++j) {
    int colH = colb + j * 16 + lr;
    float bb = b1[e * HDIM + colH];
#pragma unroll
    for (int i = 0; i < 4; ++i) {
#pragma unroll
      for (int q = 0; q < 4; ++q) {
        int rl = i * 16 + (lane >> 4) * 4 + q;
        ep[rl * 68 + j * 16 + lr] = f2bf(gelu_f(acc[i][j][q] + bb));
      }
    }
  }
  __syncthreads();
#pragma unroll
  for (int s = 0; s < 8; ++s) {
    int idx = s * 64 + lane;
    int rl = idx >> 3;
    int c8 = (idx & 7) * 8;
    int gidx = m0 + wm + rl;
    if (gidx < ce) {
      *(short8*)&hbuf[(size_t)(offe + gidx) * HDIM + colb + c8] = *(short8*)&ep[rl * 68 + c8];
    }
  }
}

// ---------------- GEMM2: ybuf = (h @ W2[e] + b2[e]) in bf16 (per expert-slot row) ----------------
__global__ __launch_bounds__(256) void expert_gemm2(
    const short* __restrict__ hbuf, const short* __restrict__ w2t,
    const float* __restrict__ b2, short* __restrict__ ybuf,
    const int* __restrict__ ctrl) {
  int raw = blockIdx.x;
  int bid = (raw & 7) * 256 + (raw >> 3);  // XCD x owns expert x
  int e = bid >> 8;
  int rem = bid & 255;
  int mt = rem >> 2;
  int nt = rem & 3;
  int ce = ctrl[e];
  int m0 = mt * 128;
  if (m0 >= ce) return;
  int offe = 0;
#pragma unroll
  for (int i = 0; i < NEXP; ++i) offe += (i < e) ? ctrl[i] : 0;

  __shared__ char smem[49152];

  int tid = threadIdx.x;
  int wave = tid >> 6;
  int lane = tid & 63;

  int sr = tid >> 2;
  int kc = (((tid & 3) ^ ((sr >> 1) & 3)) * 8);
  int ia = m0 + sr;      if (ia >= ce) ia = ce - 1;
  int ib = m0 + sr + 64; if (ib >= ce) ib = ce - 1;
  const short* gA0 = hbuf + (size_t)(offe + ia) * HDIM + kc;
  const short* gA1 = hbuf + (size_t)(offe + ib) * HDIM + kc;
  const short* gB0 = w2t + ((size_t)e * DDIM + nt * 128 + sr) * HDIM + kc;
  const short* gB1 = gB0 + (size_t)64 * HDIM;

  f32x4 acc[4][4];
#pragma unroll
  for (int i = 0; i < 4; ++i)
#pragma unroll
    for (int j = 0; j < 4; ++j) acc[i][j] = (f32x4){0.f, 0.f, 0.f, 0.f};

  int wm = (wave >> 1) * 64;
  int wn = (wave & 1) * 64;
  int lr = lane & 15;
  int kswz = ((lane >> 4) * 8) ^ (((lr >> 1) & 3) << 3);

#define STAGE2(t) do {                                                  \
    int _k = (t) * 32;                                                  \
    char* _lA = smem + ((t) % 3) * 16384 + wave * 1024;                 \
    char* _lB = _lA + 8192;                                             \
    async_lds16(gA0 + _k, _lA); async_lds16(gA1 + _k, _lA + 4096);      \
    async_lds16(gB0 + _k, _lB); async_lds16(gB1 + _k, _lB + 4096);      \
  } while (0)

  STAGE2(0);
  STAGE2(1);
#pragma unroll
  for (int t = 0; t < 32; ++t) {
    if (t < 31) asm volatile("s_waitcnt vmcnt(4)\n\ts_barrier" ::: "memory");
    else        asm volatile("s_waitcnt vmcnt(0)\n\ts_barrier" ::: "memory");
    if (t + 2 < 32) STAGE2(t + 2);
    const short* As = (const short*)(smem + (t % 3) * 16384);
    const short* Bs = As + 4096;
    short8 a[4], b[4];
#pragma unroll
    for (int i = 0; i < 4; ++i) a[i] = *(const short8*)&As[(wm + i * 16 + lr) * 32 + kswz];
#pragma unroll
    for (int j = 0; j < 4; ++j) b[j] = *(const short8*)&Bs[(wn + j * 16 + lr) * 32 + kswz];
    __builtin_amdgcn_s_setprio(1);
#pragma unroll
    for (int i = 0; i < 4; ++i)
#pragma unroll
      for (int j = 0; j < 4; ++j)
        acc[i][j] = __builtin_amdgcn_mfma_f32_16x16x32_bf16(a[i], b[j], acc[i][j], 0, 0, 0);
    __builtin_amdgcn_s_setprio(0);
    asm volatile("s_waitcnt lgkmcnt(0)" ::: "memory");
  }
#undef STAGE2
  __syncthreads();  // all K-loop reads done before epilogue reuses smem

  // ---- LDS-staged epilogue: +bias -> bf16 -> coalesced short8 stores
  short* ep = (short*)(smem + wave * 8704);
  int colb = nt * 128 + wn;
#pragma unroll
  for (int j = 0; j < 4; ++j) {
    int colD = colb + j * 16 + lr;
    float bb = b2[e * DDIM + colD];
#pragma unroll
    for (int i = 0; i < 4; ++i) {
#pragma unroll
      for (int q = 0; q < 4; ++q) {
        int rl = i * 16 + (lane >> 4) * 4 + q;
        ep[rl * 68 + j * 16 + lr] = f2bf(acc[i][j][q] + bb);
      }
    }
  }
  __syncthreads();
#pragma unroll
  for (int s = 0; s < 8; ++s) {
    int idx = s * 64 + lane;
    int rl = idx >> 3;
    int c8 = (idx & 7) * 8;
    int gidx = m0 + wm + rl;
    if (gidx < ce) {
      *(short8*)&ybuf[(size_t)(offe + gidx) * DDIM + colb + c8] = *(short8*)&ep[rl * 68 + c8];
    }
  }
}

// ---------------- combine: out[n] = w0*ybuf[slot0] + w1*ybuf[slot1] ----------------
__global__ __launch_bounds__(256) void combine_kernel(
    const short* __restrict__ ybuf, const int* __restrict__ slot_enc,
    const float* __restrict__ wf, const int* __restrict__ ctrl,
    float* __restrict__ out) {
  int wave = threadIdx.x >> 6;
  int lane = threadIdx.x & 63;
  int n = blockIdx.x * 4 + wave;
  int s0 = slot_enc[n * 2], s1 = slot_enc[n * 2 + 1];
  float w0 = wf[n * 2], w1 = wf[n * 2 + 1];
  int e0 = s0 >> 16, e1 = s1 >> 16;
  int off0 = 0, off1 = 0;
#pragma unroll
  for (int i = 0; i < NEXP; ++i) {
    int c = ctrl[i];
    off0 += (i < e0) ? c : 0;
    off1 += (i < e1) ? c : 0;
  }
  int r0 = off0 + (s0 & 0xffff);
  int r1 = off1 + (s1 & 0xffff);
  short8 a = *(const short8*)&ybuf[(size_t)r0 * DDIM + lane * 8];
  short8 b = *(const short8*)&ybuf[(size_t)r1 * DDIM + lane * 8];
  float r[8];
#pragma unroll
  for (int k = 0; k < 8; ++k) r[k] = w0 * bf2f(a[k]) + w1 * bf2f(b[k]);
  float4 o0 = {r[0], r[1], r[2], r[3]};
  float4 o1 = {r[4], r[5], r[6], r[7]};
  *(float4*)&out[(size_t)n * DDIM + lane * 8] = o0;
  *(float4*)&out[(size_t)n * DDIM + lane * 8 + 4] = o1;
}

extern "C" void kernel_launch(void* const* d_in, const int* in_sizes, int n_in,
                              void* d_out, int out_size, void* d_ws, size_t ws_size,
                              hipStream_t stream) {
  const float* x  = (const float*)d_in[0];
  const float* wg = (const float*)d_in[1];
  const float* w1 = (const float*)d_in[2];
  const float* b1 = (const float*)d_in[3];
  const float* w2 = (const float*)d_in[4];
  const float* b2 = (const float*)d_in[5];
  float* out = (float*)d_out;

  char* ws = (char*)d_ws;
  int*   ctrl = (int*)ws;                    // [0..7] counts
  int*   tok  = (int*)(ws + 1024);           // 256 KB
  int*   slot = (int*)(ws + 263168);         // 64 KB
  short* xb   = (short*)(ws + 328704);       // 8 MB
  short* w1t  = (short*)(ws + 8717312);      // 8 MB [E][H][D]
  short* w2t  = (short*)(ws + 17105920);     // 8 MB [E][D][H]
  short* hb   = (short*)(ws + 25494528);     // 32 MB
  short* yb   = (short*)(ws + 328704);       // 16 MB, ALIASES xb+w1t (dead by GEMM2)

  transpose_bf16_kernel<<<dim3(32, 16, 8), dim3(32, 8), 0, stream>>>(w1, w1t, DDIM, HDIM);
  transpose_bf16_kernel<<<dim3(16, 32, 8), dim3(32, 8), 0, stream>>>(w2, w2t, HDIM, DDIM);

  float* out_logits = out + (size_t)NTOK * DDIM;
  float* out_idx = out_logits + (size_t)NTOK * NEXP;
  float* out_w = out_idx + (size_t)NTOK * TOPK;
  router_compute<<<2048, 256, 0, stream>>>(x, wg, out_logits, out_idx, out_w, xb, ctrl);
  build_lists<<<16, 512, 0, stream>>>(out_idx, ctrl, tok, slot);

  expert_gemm1<<<4096, 256, 0, stream>>>(xb, w1t, b1, hb, ctrl, tok);
  expert_gemm2<<<2048, 256, 0, stream>>>(hb, w2t, b2, yb, ctrl);
  combine_kernel<<<2048, 256, 0, stream>>>(yb, slot, out_w, ctrl, out);
}

// Round 11
// 124.868 us; speedup vs baseline: 1.1517x; 1.0258x over previous
//
#include <hip/hip_runtime.h>
#include <hip/hip_bf16.h>

#define NTOK 8192
#define DDIM 512
#define HDIM 1024
#define NEXP 8
#define TOPK 2

typedef __attribute__((ext_vector_type(8))) short short8;
typedef __attribute__((ext_vector_type(4))) float f32x4;

// fp32 -> bf16 round-to-nearest-even (finite inputs)
__device__ __forceinline__ short f2bf(float f) {
  union { float f; unsigned u; } v; v.f = f;
  unsigned r = v.u + 0x7fffu + ((v.u >> 16) & 1u);
  return (short)(r >> 16);
}
__device__ __forceinline__ float bf2f(short s) {
  union { unsigned u; float f; } v; v.u = ((unsigned)(unsigned short)s) << 16;
  return v.f;
}

__device__ __forceinline__ void async_lds16(const void* g, void* l) {
  __builtin_amdgcn_global_load_lds(
      (const __attribute__((address_space(1))) unsigned int*)g,
      (__attribute__((address_space(3))) unsigned int*)l,
      16, 0, 0);
}

// fast GELU: v * sigmoid(2u)  (~8 VALU ops); |diff vs erf GELU| < ~1e-3, thr 0.14
__device__ __forceinline__ float gelu_f(float v) {
  float u2 = v * v;
  float z = v * (-1.5957691216f - 0.0713548163f * u2);  // -2u
  float t = __expf(z);
  return v * __builtin_amdgcn_rcpf(1.f + t);
}

// ---------------- transpose fp32 -> bf16, both weights in one launch ----------------
// z in [0,8): W1 expert z (R=512,C=1024); z in [8,16): W2 expert z-8 (R=1024,C=512)
__global__ __launch_bounds__(256) void transpose_both_kernel(
    const float* __restrict__ w1, short* __restrict__ w1t,
    const float* __restrict__ w2, short* __restrict__ w2t) {
  __shared__ float tile[32][33];
  int z = blockIdx.z;
  int R = (z < 8) ? DDIM : HDIM;
  int C = (z < 8) ? HDIM : DDIM;
  const float* s = ((z < 8) ? w1 : w2) + (size_t)(z & 7) * DDIM * HDIM;
  short* d = ((z < 8) ? w1t : w2t) + (size_t)(z & 7) * DDIM * HDIM;
  int tile_id = blockIdx.x;                 // 512 tiles of 32x32
  int ntc = C >> 5;
  int tc = tile_id % ntc, tr = tile_id / ntc;
  int c0 = tc * 32, r0 = tr * 32;
  int tx = threadIdx.x & 31, ty = threadIdx.x >> 5;
#pragma unroll
  for (int i = 0; i < 4; ++i)
    tile[ty + i * 8][tx] = s[(size_t)(r0 + ty + i * 8) * C + c0 + tx];
  __syncthreads();
#pragma unroll
  for (int i = 0; i < 4; ++i)
    d[(size_t)(c0 + ty + i * 8) * R + r0 + tx] = f2bf(tile[tx][ty + i * 8]);
}

// ---------------- router: fp32 logits, top-2, softmax; converts x->bf16; zeroes ctrl ----------------
__global__ __launch_bounds__(256) void router_compute(
    const float* __restrict__ x, const float* __restrict__ wg,
    float* __restrict__ out_logits, float* __restrict__ out_idx,
    float* __restrict__ out_w, short* __restrict__ xb, int* __restrict__ counts) {
  if (blockIdx.x == 0 && threadIdx.x < NEXP) counts[threadIdx.x] = 0;  // ordered before build_lists
  int wave = threadIdx.x >> 6;
  int lane = threadIdx.x & 63;
  int n = blockIdx.x * 4 + wave;

  const float* xrow = x + (size_t)n * DDIM;
  const float4* xv = (const float4*)xrow;
  float4 xa = xv[lane * 2], xbv = xv[lane * 2 + 1];
  float xs[8] = {xa.x, xa.y, xa.z, xa.w, xbv.x, xbv.y, xbv.z, xbv.w};

  short8 xc;
#pragma unroll
  for (int j = 0; j < 8; ++j) xc[j] = f2bf(xs[j]);
  *(short8*)(xb + (size_t)n * DDIM + lane * 8) = xc;

  float acc[8] = {0, 0, 0, 0, 0, 0, 0, 0};
#pragma unroll
  for (int j = 0; j < 8; ++j) {
    const float4* wr = (const float4*)(wg + (size_t)(lane * 8 + j) * NEXP);
    float4 w0 = wr[0], w1 = wr[1];
    float xj = xs[j];
    acc[0] += xj * w0.x; acc[1] += xj * w0.y; acc[2] += xj * w0.z; acc[3] += xj * w0.w;
    acc[4] += xj * w1.x; acc[5] += xj * w1.y; acc[6] += xj * w1.z; acc[7] += xj * w1.w;
  }
#pragma unroll
  for (int m = 32; m >= 1; m >>= 1) {
#pragma unroll
    for (int e = 0; e < 8; ++e) acc[e] += __shfl_xor(acc[e], m);
  }
  if (lane == 0) {
#pragma unroll
    for (int e = 0; e < 8; ++e) out_logits[(size_t)n * NEXP + e] = acc[e];
    int i1 = 0; float v1 = acc[0];
#pragma unroll
    for (int e = 1; e < 8; ++e) if (acc[e] > v1) { v1 = acc[e]; i1 = e; }
    int i2 = -1; float v2 = -3.4e38f;
#pragma unroll
    for (int e = 0; e < 8; ++e) if (e != i1 && acc[e] > v2) { v2 = acc[e]; i2 = e; }
    float ex = expf(v2 - v1);
    float s = 1.f / (1.f + ex);
    out_idx[n * 2] = (float)i1; out_idx[n * 2 + 1] = (float)i2;
    out_w[n * 2] = s; out_w[n * 2 + 1] = ex * s;
  }
}

// ---------------- build per-expert token lists (wave-aggregated atomics) ----------------
__global__ __launch_bounds__(512) void build_lists(
    const float* __restrict__ idxf,
    int* __restrict__ counts, int* __restrict__ tok_list, int* __restrict__ slot_enc) {
  int t = blockIdx.x * 512 + threadIdx.x;
  int lane = threadIdx.x & 63;
  float2 iv = *(const float2*)(idxf + (size_t)t * 2);
  int es[2] = {(int)iv.x, (int)iv.y};
#pragma unroll
  for (int s = 0; s < 2; ++s) {
    int e = es[s];
#pragma unroll
    for (int ex = 0; ex < NEXP; ++ex) {
      unsigned long long m = __ballot(e == ex);
      if (e == ex) {
        int leader = __ffsll(m) - 1;
        int base = 0;
        if (lane == leader) base = atomicAdd(&counts[ex], __popcll(m));
        base = __shfl(base, leader);
        int rank = __popcll(m & ((1ull << lane) - 1ull));
        tok_list[ex * NTOK + base + rank] = t;
        slot_enc[t * 2 + s] = (ex << 16) | (base + rank);
      }
    }
  }
}

// ---------------- GEMM1: h = GELU(gather(x) @ W1[e] + b1[e]) -> bf16 hbuf ----------------
// 2-buf staging (34.8KB LDS -> 4 blocks/CU); one fused vmcnt(0)+barrier per K-step;
// trailing lgkmcnt(0); pre-swizzled source + swizzled ds_read (0 conflicts); XCD = expert.
__global__ __launch_bounds__(256) void expert_gemm1(
    const short* __restrict__ xb, const short* __restrict__ w1t,
    const float* __restrict__ b1, short* __restrict__ hbuf,
    const int* __restrict__ ctrl, const int* __restrict__ tok_list) {
  int raw = blockIdx.x;
  int bid = (raw & 7) * 512 + (raw >> 3);  // bijective: XCD x owns expert x
  int e = bid >> 9;
  int rem = bid & 511;
  int mt = rem >> 3;
  int nt = rem & 7;
  int ce = ctrl[e];
  int m0 = mt * 128;
  if (m0 >= ce) return;
  int offe = 0;
#pragma unroll
  for (int i = 0; i < NEXP; ++i) offe += (i < e) ? ctrl[i] : 0;

  // LDS: 2 staging buffers x 16KB (As 8K | Bs 8K); epilogue uses [0,34816)
  __shared__ char smem[34816];

  int tid = threadIdx.x;
  int wave = tid >> 6;
  int lane = tid & 63;

  int sr = tid >> 2;
  // Pre-swizzled source: lane writes LDS chunk (sr, tid&3); fetch the global chunk
  // that belongs there under involution chunk^=((row>>1)&3)
  int kc = (((tid & 3) ^ ((sr >> 1) & 3)) * 8);
  int ia = m0 + sr;      if (ia >= ce) ia = ce - 1;
  int ib = m0 + sr + 64; if (ib >= ce) ib = ce - 1;
  const short* gA0 = xb + (size_t)tok_list[e * NTOK + ia] * DDIM + kc;
  const short* gA1 = xb + (size_t)tok_list[e * NTOK + ib] * DDIM + kc;
  const short* gB0 = w1t + ((size_t)e * HDIM + nt * 128 + sr) * DDIM + kc;
  const short* gB1 = gB0 + (size_t)64 * DDIM;

  f32x4 acc[4][4];
#pragma unroll
  for (int i = 0; i < 4; ++i)
#pragma unroll
    for (int j = 0; j < 4; ++j) acc[i][j] = (f32x4){0.f, 0.f, 0.f, 0.f};

  int wm = (wave >> 1) * 64;
  int wn = (wave & 1) * 64;
  int lr = lane & 15;
  int kswz = ((lane >> 4) * 8) ^ (((lr >> 1) & 3) << 3);

#define STAGE1(t) do {                                                  \
    int _k = (t) * 32;                                                  \
    char* _lA = smem + (((t) & 1) << 14) + wave * 1024;                 \
    char* _lB = _lA + 8192;                                             \
    async_lds16(gA0 + _k, _lA); async_lds16(gA1 + _k, _lA + 4096);      \
    async_lds16(gB0 + _k, _lB); async_lds16(gB1 + _k, _lB + 4096);      \
  } while (0)

  STAGE1(0);
#pragma unroll
  for (int t = 0; t < 16; ++t) {
    // Tile t's DMA (all waves) landed once every wave passes this barrier.
    asm volatile("s_waitcnt vmcnt(0)\n\ts_barrier" ::: "memory");
    // Overwriting buf[(t+1)&1] (read at t-1) is safe: every wave drained
    // lgkmcnt(0) at the end of iter t-1, BEFORE arriving at the barrier above.
    if (t + 1 < 16) STAGE1(t + 1);
    const short* As = (const short*)(smem + ((t & 1) << 14));
    const short* Bs = As + 4096;
    short8 a[4], b[4];
#pragma unroll
    for (int i = 0; i < 4; ++i) a[i] = *(const short8*)&As[(wm + i * 16 + lr) * 32 + kswz];
#pragma unroll
    for (int j = 0; j < 4; ++j) b[j] = *(const short8*)&Bs[(wn + j * 16 + lr) * 32 + kswz];
    // Compiler emits counted lgkmcnt before each first use (read/MFMA interleave).
    __builtin_amdgcn_s_setprio(1);
#pragma unroll
    for (int i = 0; i < 4; ++i)
#pragma unroll
      for (int j = 0; j < 4; ++j)
        acc[i][j] = __builtin_amdgcn_mfma_f32_16x16x32_bf16(a[i], b[j], acc[i][j], 0, 0, 0);
    __builtin_amdgcn_s_setprio(0);
    // Invariant: this wave's ds_reads are SERVICED before it reaches the next barrier.
    asm volatile("s_waitcnt lgkmcnt(0)" ::: "memory");
  }
#undef STAGE1
  __syncthreads();  // all K-loop reads done before epilogue reuses smem

  // ---- LDS-staged epilogue: GELU -> bf16 -> per-wave 64x68 tile -> coalesced short8 stores
  short* ep = (short*)(smem + wave * 8704);
  int colb = nt * 128 + wn;
#pragma unroll
  for (int j = 0; j < 4; ++j) {
    int colH = colb + j * 16 + lr;
    float bb = b1[e * HDIM + colH];
#pragma unroll
    for (int i = 0; i < 4; ++i) {
#pragma unroll
      for (int q = 0; q < 4; ++q) {
        int rl = i * 16 + (lane >> 4) * 4 + q;
        ep[rl * 68 + j * 16 + lr] = f2bf(gelu_f(acc[i][j][q] + bb));
      }
    }
  }
  __syncthreads();
#pragma unroll
  for (int s = 0; s < 8; ++s) {
    int idx = s * 64 + lane;
    int rl = idx >> 3;
    int c8 = (idx & 7) * 8;
    int gidx = m0 + wm + rl;
    if (gidx < ce) {
      *(short8*)&hbuf[(size_t)(offe + gidx) * HDIM + colb + c8] = *(short8*)&ep[rl * 68 + c8];
    }
  }
}

// ---------------- GEMM2: ybuf = (h @ W2[e] + b2[e]) in bf16 (per expert-slot row) ----------------
__global__ __launch_bounds__(256) void expert_gemm2(
    const short* __restrict__ hbuf, const short* __restrict__ w2t,
    const float* __restrict__ b2, short* __restrict__ ybuf,
    const int* __restrict__ ctrl) {
  int raw = blockIdx.x;
  int bid = (raw & 7) * 256 + (raw >> 3);  // XCD x owns expert x
  int e = bid >> 8;
  int rem = bid & 255;
  int mt = rem >> 2;
  int nt = rem & 3;
  int ce = ctrl[e];
  int m0 = mt * 128;
  if (m0 >= ce) return;
  int offe = 0;
#pragma unroll
  for (int i = 0; i < NEXP; ++i) offe += (i < e) ? ctrl[i] : 0;

  __shared__ char smem[34816];

  int tid = threadIdx.x;
  int wave = tid >> 6;
  int lane = tid & 63;

  int sr = tid >> 2;
  int kc = (((tid & 3) ^ ((sr >> 1) & 3)) * 8);
  int ia = m0 + sr;      if (ia >= ce) ia = ce - 1;
  int ib = m0 + sr + 64; if (ib >= ce) ib = ce - 1;
  const short* gA0 = hbuf + (size_t)(offe + ia) * HDIM + kc;
  const short* gA1 = hbuf + (size_t)(offe + ib) * HDIM + kc;
  const short* gB0 = w2t + ((size_t)e * DDIM + nt * 128 + sr) * HDIM + kc;
  const short* gB1 = gB0 + (size_t)64 * HDIM;

  f32x4 acc[4][4];
#pragma unroll
  for (int i = 0; i < 4; ++i)
#pragma unroll
    for (int j = 0; j < 4; ++j) acc[i][j] = (f32x4){0.f, 0.f, 0.f, 0.f};

  int wm = (wave >> 1) * 64;
  int wn = (wave & 1) * 64;
  int lr = lane & 15;
  int kswz = ((lane >> 4) * 8) ^ (((lr >> 1) & 3) << 3);

#define STAGE2(t) do {                                                  \
    int _k = (t) * 32;                                                  \
    char* _lA = smem + (((t) & 1) << 14) + wave * 1024;                 \
    char* _lB = _lA + 8192;                                             \
    async_lds16(gA0 + _k, _lA); async_lds16(gA1 + _k, _lA + 4096);      \
    async_lds16(gB0 + _k, _lB); async_lds16(gB1 + _k, _lB + 4096);      \
  } while (0)

  STAGE2(0);
#pragma unroll
  for (int t = 0; t < 32; ++t) {
    asm volatile("s_waitcnt vmcnt(0)\n\ts_barrier" ::: "memory");
    if (t + 1 < 32) STAGE2(t + 1);
    const short* As = (const short*)(smem + ((t & 1) << 14));
    const short* Bs = As + 4096;
    short8 a[4], b[4];
#pragma unroll
    for (int i = 0; i < 4; ++i) a[i] = *(const short8*)&As[(wm + i * 16 + lr) * 32 + kswz];
#pragma unroll
    for (int j = 0; j < 4; ++j) b[j] = *(const short8*)&Bs[(wn + j * 16 + lr) * 32 + kswz];
    __builtin_amdgcn_s_setprio(1);
#pragma unroll
    for (int i = 0; i < 4; ++i)
#pragma unroll
      for (int j = 0; j < 4; ++j)
        acc[i][j] = __builtin_amdgcn_mfma_f32_16x16x32_bf16(a[i], b[j], acc[i][j], 0, 0, 0);
    __builtin_amdgcn_s_setprio(0);
    asm volatile("s_waitcnt lgkmcnt(0)" ::: "memory");
  }
#undef STAGE2
  __syncthreads();  // all K-loop reads done before epilogue reuses smem

  // ---- LDS-staged epilogue: +bias -> bf16 -> coalesced short8 stores
  short* ep = (short*)(smem + wave * 8704);
  int colb = nt * 128 + wn;
#pragma unroll
  for (int j = 0; j < 4; ++j) {
    int colD = colb + j * 16 + lr;
    float bb = b2[e * DDIM + colD];
#pragma unroll
    for (int i = 0; i < 4; ++i) {
#pragma unroll
      for (int q = 0; q < 4; ++q) {
        int rl = i * 16 + (lane >> 4) * 4 + q;
        ep[rl * 68 + j * 16 + lr] = f2bf(acc[i][j][q] + bb);
      }
    }
  }
  __syncthreads();
#pragma unroll
  for (int s = 0; s < 8; ++s) {
    int idx = s * 64 + lane;
    int rl = idx >> 3;
    int c8 = (idx & 7) * 8;
    int gidx = m0 + wm + rl;
    if (gidx < ce) {
      *(short8*)&ybuf[(size_t)(offe + gidx) * DDIM + colb + c8] = *(short8*)&ep[rl * 68 + c8];
    }
  }
}

// ---------------- combine: out[n] = w0*ybuf[slot0] + w1*ybuf[slot1] ----------------
__global__ __launch_bounds__(256) void combine_kernel(
    const short* __restrict__ ybuf, const int* __restrict__ slot_enc,
    const float* __restrict__ wf, const int* __restrict__ ctrl,
    float* __restrict__ out) {
  int wave = threadIdx.x >> 6;
  int lane = threadIdx.x & 63;
  int n = blockIdx.x * 4 + wave;
  int s0 = slot_enc[n * 2], s1 = slot_enc[n * 2 + 1];
  float w0 = wf[n * 2], w1 = wf[n * 2 + 1];
  int e0 = s0 >> 16, e1 = s1 >> 16;
  int off0 = 0, off1 = 0;
#pragma unroll
  for (int i = 0; i < NEXP; ++i) {
    int c = ctrl[i];
    off0 += (i < e0) ? c : 0;
    off1 += (i < e1) ? c : 0;
  }
  int r0 = off0 + (s0 & 0xffff);
  int r1 = off1 + (s1 & 0xffff);
  short8 a = *(const short8*)&ybuf[(size_t)r0 * DDIM + lane * 8];
  short8 b = *(const short8*)&ybuf[(size_t)r1 * DDIM + lane * 8];
  float r[8];
#pragma unroll
  for (int k = 0; k < 8; ++k) r[k] = w0 * bf2f(a[k]) + w1 * bf2f(b[k]);
  float4 o0 = {r[0], r[1], r[2], r[3]};
  float4 o1 = {r[4], r[5], r[6], r[7]};
  *(float4*)&out[(size_t)n * DDIM + lane * 8] = o0;
  *(float4*)&out[(size_t)n * DDIM + lane * 8 + 4] = o1;
}

extern "C" void kernel_launch(void* const* d_in, const int* in_sizes, int n_in,
                              void* d_out, int out_size, void* d_ws, size_t ws_size,
                              hipStream_t stream) {
  const float* x  = (const float*)d_in[0];
  const float* wg = (const float*)d_in[1];
  const float* w1 = (const float*)d_in[2];
  const float* b1 = (const float*)d_in[3];
  const float* w2 = (const float*)d_in[4];
  const float* b2 = (const float*)d_in[5];
  float* out = (float*)d_out;

  char* ws = (char*)d_ws;
  int*   ctrl = (int*)ws;                    // [0..7] counts
  int*   tok  = (int*)(ws + 1024);           // 256 KB
  int*   slot = (int*)(ws + 263168);         // 64 KB
  short* xb   = (short*)(ws + 328704);       // 8 MB
  short* w1t  = (short*)(ws + 8717312);      // 8 MB [E][H][D]
  short* w2t  = (short*)(ws + 17105920);     // 8 MB [E][D][H]
  short* hb   = (short*)(ws + 25494528);     // 32 MB
  short* yb   = (short*)(ws + 328704);       // 16 MB, ALIASES xb+w1t (dead by GEMM2)

  transpose_both_kernel<<<dim3(512, 1, 16), 256, 0, stream>>>(w1, w1t, w2, w2t);

  float* out_logits = out + (size_t)NTOK * DDIM;
  float* out_idx = out_logits + (size_t)NTOK * NEXP;
  float* out_w = out_idx + (size_t)NTOK * TOPK;
  router_compute<<<2048, 256, 0, stream>>>(x, wg, out_logits, out_idx, out_w, xb, ctrl);
  build_lists<<<16, 512, 0, stream>>>(out_idx, ctrl, tok, slot);

  expert_gemm1<<<4096, 256, 0, stream>>>(xb, w1t, b1, hb, ctrl, tok);
  expert_gemm2<<<2048, 256, 0, stream>>>(hb, w2t, b2, yb, ctrl);
  combine_kernel<<<2048, 256, 0, stream>>>(yb, slot, out_w, ctrl, out);
}

// Round 12
// 123.379 us; speedup vs baseline: 1.1656x; 1.0121x over previous
//
#include <hip/hip_runtime.h>
#include <hip/hip_bf16.h>

#define NTOK 8192
#define DDIM 512
#define HDIM 1024
#define NEXP 8
#define TOPK 2

typedef __attribute__((ext_vector_type(8))) short short8;
typedef __attribute__((ext_vector_type(4))) float f32x4;

// fp32 -> bf16 round-to-nearest-even (finite inputs)
__device__ __forceinline__ short f2bf(float f) {
  union { float f; unsigned u; } v; v.f = f;
  unsigned r = v.u + 0x7fffu + ((v.u >> 16) & 1u);
  return (short)(r >> 16);
}
__device__ __forceinline__ float bf2f(short s) {
  union { unsigned u; float f; } v; v.u = ((unsigned)(unsigned short)s) << 16;
  return v.f;
}

__device__ __forceinline__ void async_lds16(const void* g, void* l) {
  __builtin_amdgcn_global_load_lds(
      (const __attribute__((address_space(1))) unsigned int*)g,
      (__attribute__((address_space(3))) unsigned int*)l,
      16, 0, 0);
}

// fast GELU: v * sigmoid(2u)  (~8 VALU ops); |diff vs erf GELU| < ~1e-3, thr 0.14
__device__ __forceinline__ float gelu_f(float v) {
  float u2 = v * v;
  float z = v * (-1.5957691216f - 0.0713548163f * u2);  // -2u
  float t = __expf(z);
  return v * __builtin_amdgcn_rcpf(1.f + t);
}

// ---------------- prep: weight transposes (blocks 0..8191) + router (blocks 8192..10239) ----------
// Fusing the two memory-bound phases lets them share HBM BW instead of serializing.
__global__ __launch_bounds__(256) void prep_kernel(
    const float* __restrict__ w1, short* __restrict__ w1t,
    const float* __restrict__ w2, short* __restrict__ w2t,
    const float* __restrict__ x, const float* __restrict__ wg,
    float* __restrict__ out_logits, float* __restrict__ out_idx,
    float* __restrict__ out_w, short* __restrict__ xb, int* __restrict__ counts) {
  __shared__ float tile[32][33];
  int raw = blockIdx.x;
  if (raw < 8192) {
    // ---- transpose fp32 [R][C] -> bf16 [C][R]; z<8: W1 (512x1024), z>=8: W2 (1024x512)
    int z = raw >> 9;
    int tile_id = raw & 511;
    int R = (z < 8) ? DDIM : HDIM;
    int C = (z < 8) ? HDIM : DDIM;
    const float* s = ((z < 8) ? w1 : w2) + (size_t)(z & 7) * DDIM * HDIM;
    short* d = ((z < 8) ? w1t : w2t) + (size_t)(z & 7) * DDIM * HDIM;
    int tc = (z < 8) ? (tile_id & 31) : (tile_id & 15);
    int tr = (z < 8) ? (tile_id >> 5) : (tile_id >> 4);
    int c0 = tc * 32, r0 = tr * 32;
    int tx = threadIdx.x & 31, ty = threadIdx.x >> 5;
#pragma unroll
    for (int i = 0; i < 4; ++i)
      tile[ty + i * 8][tx] = s[(size_t)(r0 + ty + i * 8) * C + c0 + tx];
    __syncthreads();
#pragma unroll
    for (int i = 0; i < 4; ++i)
      d[(size_t)(c0 + ty + i * 8) * R + r0 + tx] = f2bf(tile[tx][ty + i * 8]);
    return;
  }
  // ---- router: fp32 logits, top-2, softmax; converts x->bf16; zeroes ctrl
  int rb = raw - 8192;
  if (rb == 0 && threadIdx.x < NEXP) counts[threadIdx.x] = 0;  // ordered before build_lists
  int wave = threadIdx.x >> 6;
  int lane = threadIdx.x & 63;
  int n = rb * 4 + wave;

  const float* xrow = x + (size_t)n * DDIM;
  const float4* xv = (const float4*)xrow;
  float4 xa = xv[lane * 2], xbv = xv[lane * 2 + 1];
  float xs[8] = {xa.x, xa.y, xa.z, xa.w, xbv.x, xbv.y, xbv.z, xbv.w};

  short8 xc;
#pragma unroll
  for (int j = 0; j < 8; ++j) xc[j] = f2bf(xs[j]);
  *(short8*)(xb + (size_t)n * DDIM + lane * 8) = xc;

  float acc[8] = {0, 0, 0, 0, 0, 0, 0, 0};
#pragma unroll
  for (int j = 0; j < 8; ++j) {
    const float4* wr = (const float4*)(wg + (size_t)(lane * 8 + j) * NEXP);
    float4 w0 = wr[0], w1v = wr[1];
    float xj = xs[j];
    acc[0] += xj * w0.x; acc[1] += xj * w0.y; acc[2] += xj * w0.z; acc[3] += xj * w0.w;
    acc[4] += xj * w1v.x; acc[5] += xj * w1v.y; acc[6] += xj * w1v.z; acc[7] += xj * w1v.w;
  }
#pragma unroll
  for (int m = 32; m >= 1; m >>= 1) {
#pragma unroll
    for (int e = 0; e < 8; ++e) acc[e] += __shfl_xor(acc[e], m);
  }
  if (lane == 0) {
#pragma unroll
    for (int e = 0; e < 8; ++e) out_logits[(size_t)n * NEXP + e] = acc[e];
    int i1 = 0; float v1 = acc[0];
#pragma unroll
    for (int e = 1; e < 8; ++e) if (acc[e] > v1) { v1 = acc[e]; i1 = e; }
    int i2 = -1; float v2 = -3.4e38f;
#pragma unroll
    for (int e = 0; e < 8; ++e) if (e != i1 && acc[e] > v2) { v2 = acc[e]; i2 = e; }
    float ex = expf(v2 - v1);
    float s = 1.f / (1.f + ex);
    out_idx[n * 2] = (float)i1; out_idx[n * 2 + 1] = (float)i2;
    out_w[n * 2] = s; out_w[n * 2 + 1] = ex * s;
  }
}

// ---------------- build per-expert token lists (wave-aggregated atomics) ----------------
__global__ __launch_bounds__(512) void build_lists(
    const float* __restrict__ idxf,
    int* __restrict__ counts, int* __restrict__ tok_list, int* __restrict__ slot_enc) {
  int t = blockIdx.x * 512 + threadIdx.x;
  int lane = threadIdx.x & 63;
  float2 iv = *(const float2*)(idxf + (size_t)t * 2);
  int es[2] = {(int)iv.x, (int)iv.y};
#pragma unroll
  for (int s = 0; s < 2; ++s) {
    int e = es[s];
#pragma unroll
    for (int ex = 0; ex < NEXP; ++ex) {
      unsigned long long m = __ballot(e == ex);
      if (e == ex) {
        int leader = __ffsll(m) - 1;
        int base = 0;
        if (lane == leader) base = atomicAdd(&counts[ex], __popcll(m));
        base = __shfl(base, leader);
        int rank = __popcll(m & ((1ull << lane) - 1ull));
        tok_list[ex * NTOK + base + rank] = t;
        slot_enc[t * 2 + s] = (ex << 16) | (base + rank);
      }
    }
  }
}

// ---------------- GEMM1: h = GELU(gather(x) @ W1[e] + b1[e]) -> bf16 hbuf ----------------
// 2-buf staging (34.8KB LDS -> 4 blocks/CU); one fused vmcnt(0)+barrier per K-step;
// trailing lgkmcnt(0); pre-swizzled source + swizzled ds_read (0 conflicts); XCD = expert.
__global__ __launch_bounds__(256) void expert_gemm1(
    const short* __restrict__ xb, const short* __restrict__ w1t,
    const float* __restrict__ b1, short* __restrict__ hbuf,
    const int* __restrict__ ctrl, const int* __restrict__ tok_list) {
  int raw = blockIdx.x;
  int bid = (raw & 7) * 512 + (raw >> 3);  // bijective: XCD x owns expert x
  int e = bid >> 9;
  int rem = bid & 511;
  int mt = rem >> 3;
  int nt = rem & 7;
  int ce = ctrl[e];
  int m0 = mt * 128;
  if (m0 >= ce) return;
  int offe = 0;
#pragma unroll
  for (int i = 0; i < NEXP; ++i) offe += (i < e) ? ctrl[i] : 0;

  // LDS: 2 staging buffers x 16KB (As 8K | Bs 8K); epilogue uses [0,34816)
  __shared__ char smem[34816];

  int tid = threadIdx.x;
  int wave = tid >> 6;
  int lane = tid & 63;

  int sr = tid >> 2;
  // Pre-swizzled source: lane writes LDS chunk (sr, tid&3); fetch the global chunk
  // that belongs there under involution chunk^=((row>>1)&3)
  int kc = (((tid & 3) ^ ((sr >> 1) & 3)) * 8);
  int ia = m0 + sr;      if (ia >= ce) ia = ce - 1;
  int ib = m0 + sr + 64; if (ib >= ce) ib = ce - 1;
  const short* gA0 = xb + (size_t)tok_list[e * NTOK + ia] * DDIM + kc;
  const short* gA1 = xb + (size_t)tok_list[e * NTOK + ib] * DDIM + kc;
  const short* gB0 = w1t + ((size_t)e * HDIM + nt * 128 + sr) * DDIM + kc;
  const short* gB1 = gB0 + (size_t)64 * DDIM;

  f32x4 acc[4][4];
#pragma unroll
  for (int i = 0; i < 4; ++i)
#pragma unroll
    for (int j = 0; j < 4; ++j) acc[i][j] = (f32x4){0.f, 0.f, 0.f, 0.f};

  int wm = (wave >> 1) * 64;
  int wn = (wave & 1) * 64;
  int lr = lane & 15;
  int kswz = ((lane >> 4) * 8) ^ (((lr >> 1) & 3) << 3);

  // Hoist bias loads: issue before the K-loop so their latency hides under compute.
  int colb = nt * 128 + wn;
  float bb[4];
#pragma unroll
  for (int j = 0; j < 4; ++j) bb[j] = b1[e * HDIM + colb + j * 16 + lr];

#define STAGE1(t) do {                                                  \
    int _k = (t) * 32;                                                  \
    char* _lA = smem + (((t) & 1) << 14) + wave * 1024;                 \
    char* _lB = _lA + 8192;                                             \
    async_lds16(gA0 + _k, _lA); async_lds16(gA1 + _k, _lA + 4096);      \
    async_lds16(gB0 + _k, _lB); async_lds16(gB1 + _k, _lB + 4096);      \
  } while (0)

  STAGE1(0);
#pragma unroll
  for (int t = 0; t < 16; ++t) {
    // Tile t's DMA (all waves) landed once every wave passes this barrier.
    asm volatile("s_waitcnt vmcnt(0)\n\ts_barrier" ::: "memory");
    // Overwriting buf[(t+1)&1] (read at t-1) is safe: every wave drained
    // lgkmcnt(0) at the end of iter t-1, BEFORE arriving at the barrier above.
    if (t + 1 < 16) STAGE1(t + 1);
    const short* As = (const short*)(smem + ((t & 1) << 14));
    const short* Bs = As + 4096;
    short8 a[4], b[4];
#pragma unroll
    for (int i = 0; i < 4; ++i) a[i] = *(const short8*)&As[(wm + i * 16 + lr) * 32 + kswz];
#pragma unroll
    for (int j = 0; j < 4; ++j) b[j] = *(const short8*)&Bs[(wn + j * 16 + lr) * 32 + kswz];
    // Compiler emits counted lgkmcnt before each first use (read/MFMA interleave).
    __builtin_amdgcn_s_setprio(1);
#pragma unroll
    for (int i = 0; i < 4; ++i)
#pragma unroll
      for (int j = 0; j < 4; ++j)
        acc[i][j] = __builtin_amdgcn_mfma_f32_16x16x32_bf16(a[i], b[j], acc[i][j], 0, 0, 0);
    __builtin_amdgcn_s_setprio(0);
    // Invariant: this wave's ds_reads are SERVICED before it reaches the next barrier.
    asm volatile("s_waitcnt lgkmcnt(0)" ::: "memory");
  }
#undef STAGE1
  __syncthreads();  // all K-loop reads done before epilogue reuses smem

  // ---- LDS-staged epilogue: GELU -> bf16 -> per-wave 64x68 tile -> coalesced short8 stores
  short* ep = (short*)(smem + wave * 8704);
#pragma unroll
  for (int j = 0; j < 4; ++j) {
#pragma unroll
    for (int i = 0; i < 4; ++i) {
#pragma unroll
      for (int q = 0; q < 4; ++q) {
        int rl = i * 16 + (lane >> 4) * 4 + q;
        ep[rl * 68 + j * 16 + lr] = f2bf(gelu_f(acc[i][j][q] + bb[j]));
      }
    }
  }
  __syncthreads();
#pragma unroll
  for (int s = 0; s < 8; ++s) {
    int idx = s * 64 + lane;
    int rl = idx >> 3;
    int c8 = (idx & 7) * 8;
    int gidx = m0 + wm + rl;
    if (gidx < ce) {
      *(short8*)&hbuf[(size_t)(offe + gidx) * HDIM + colb + c8] = *(short8*)&ep[rl * 68 + c8];
    }
  }
}

// ---------------- GEMM2: ybuf = (h @ W2[e] + b2[e]) in bf16 (per expert-slot row) ----------------
__global__ __launch_bounds__(256) void expert_gemm2(
    const short* __restrict__ hbuf, const short* __restrict__ w2t,
    const float* __restrict__ b2, short* __restrict__ ybuf,
    const int* __restrict__ ctrl) {
  int raw = blockIdx.x;
  int bid = (raw & 7) * 256 + (raw >> 3);  // XCD x owns expert x
  int e = bid >> 8;
  int rem = bid & 255;
  int mt = rem >> 2;
  int nt = rem & 3;
  int ce = ctrl[e];
  int m0 = mt * 128;
  if (m0 >= ce) return;
  int offe = 0;
#pragma unroll
  for (int i = 0; i < NEXP; ++i) offe += (i < e) ? ctrl[i] : 0;

  __shared__ char smem[34816];

  int tid = threadIdx.x;
  int wave = tid >> 6;
  int lane = tid & 63;

  int sr = tid >> 2;
  int kc = (((tid & 3) ^ ((sr >> 1) & 3)) * 8);
  int ia = m0 + sr;      if (ia >= ce) ia = ce - 1;
  int ib = m0 + sr + 64; if (ib >= ce) ib = ce - 1;
  const short* gA0 = hbuf + (size_t)(offe + ia) * HDIM + kc;
  const short* gA1 = hbuf + (size_t)(offe + ib) * HDIM + kc;
  const short* gB0 = w2t + ((size_t)e * DDIM + nt * 128 + sr) * HDIM + kc;
  const short* gB1 = gB0 + (size_t)64 * HDIM;

  f32x4 acc[4][4];
#pragma unroll
  for (int i = 0; i < 4; ++i)
#pragma unroll
    for (int j = 0; j < 4; ++j) acc[i][j] = (f32x4){0.f, 0.f, 0.f, 0.f};

  int wm = (wave >> 1) * 64;
  int wn = (wave & 1) * 64;
  int lr = lane & 15;
  int kswz = ((lane >> 4) * 8) ^ (((lr >> 1) & 3) << 3);

  int colb = nt * 128 + wn;
  float bb[4];
#pragma unroll
  for (int j = 0; j < 4; ++j) bb[j] = b2[e * DDIM + colb + j * 16 + lr];

#define STAGE2(t) do {                                                  \
    int _k = (t) * 32;                                                  \
    char* _lA = smem + (((t) & 1) << 14) + wave * 1024;                 \
    char* _lB = _lA + 8192;                                             \
    async_lds16(gA0 + _k, _lA); async_lds16(gA1 + _k, _lA + 4096);      \
    async_lds16(gB0 + _k, _lB); async_lds16(gB1 + _k, _lB + 4096);      \
  } while (0)

  STAGE2(0);
#pragma unroll
  for (int t = 0; t < 32; ++t) {
    asm volatile("s_waitcnt vmcnt(0)\n\ts_barrier" ::: "memory");
    if (t + 1 < 32) STAGE2(t + 1);
    const short* As = (const short*)(smem + ((t & 1) << 14));
    const short* Bs = As + 4096;
    short8 a[4], b[4];
#pragma unroll
    for (int i = 0; i < 4; ++i) a[i] = *(const short8*)&As[(wm + i * 16 + lr) * 32 + kswz];
#pragma unroll
    for (int j = 0; j < 4; ++j) b[j] = *(const short8*)&Bs[(wn + j * 16 + lr) * 32 + kswz];
    __builtin_amdgcn_s_setprio(1);
#pragma unroll
    for (int i = 0; i < 4; ++i)
#pragma unroll
      for (int j = 0; j < 4; ++j)
        acc[i][j] = __builtin_amdgcn_mfma_f32_16x16x32_bf16(a[i], b[j], acc[i][j], 0, 0, 0);
    __builtin_amdgcn_s_setprio(0);
    asm volatile("s_waitcnt lgkmcnt(0)" ::: "memory");
  }
#undef STAGE2
  __syncthreads();  // all K-loop reads done before epilogue reuses smem

  // ---- LDS-staged epilogue: +bias -> bf16 -> coalesced short8 stores
  short* ep = (short*)(smem + wave * 8704);
#pragma unroll
  for (int j = 0; j < 4; ++j) {
#pragma unroll
    for (int i = 0; i < 4; ++i) {
#pragma unroll
      for (int q = 0; q < 4; ++q) {
        int rl = i * 16 + (lane >> 4) * 4 + q;
        ep[rl * 68 + j * 16 + lr] = f2bf(acc[i][j][q] + bb[j]);
      }
    }
  }
  __syncthreads();
#pragma unroll
  for (int s = 0; s < 8; ++s) {
    int idx = s * 64 + lane;
    int rl = idx >> 3;
    int c8 = (idx & 7) * 8;
    int gidx = m0 + wm + rl;
    if (gidx < ce) {
      *(short8*)&ybuf[(size_t)(offe + gidx) * DDIM + colb + c8] = *(short8*)&ep[rl * 68 + c8];
    }
  }
}

// ---------------- combine: out[n] = w0*ybuf[slot0] + w1*ybuf[slot1] ----------------
__global__ __launch_bounds__(256) void combine_kernel(
    const short* __restrict__ ybuf, const int* __restrict__ slot_enc,
    const float* __restrict__ wf, const int* __restrict__ ctrl,
    float* __restrict__ out) {
  int wave = threadIdx.x >> 6;
  int lane = threadIdx.x & 63;
  int n = blockIdx.x * 4 + wave;
  int s0 = slot_enc[n * 2], s1 = slot_enc[n * 2 + 1];
  float w0 = wf[n * 2], w1 = wf[n * 2 + 1];
  int e0 = s0 >> 16, e1 = s1 >> 16;
  int off0 = 0, off1 = 0;
#pragma unroll
  for (int i = 0; i < NEXP; ++i) {
    int c = ctrl[i];
    off0 += (i < e0) ? c : 0;
    off1 += (i < e1) ? c : 0;
  }
  int r0 = off0 + (s0 & 0xffff);
  int r1 = off1 + (s1 & 0xffff);
  short8 a = *(const short8*)&ybuf[(size_t)r0 * DDIM + lane * 8];
  short8 b = *(const short8*)&ybuf[(size_t)r1 * DDIM + lane * 8];
  float r[8];
#pragma unroll
  for (int k = 0; k < 8; ++k) r[k] = w0 * bf2f(a[k]) + w1 * bf2f(b[k]);
  float4 o0 = {r[0], r[1], r[2], r[3]};
  float4 o1 = {r[4], r[5], r[6], r[7]};
  *(float4*)&out[(size_t)n * DDIM + lane * 8] = o0;
  *(float4*)&out[(size_t)n * DDIM + lane * 8 + 4] = o1;
}

extern "C" void kernel_launch(void* const* d_in, const int* in_sizes, int n_in,
                              void* d_out, int out_size, void* d_ws, size_t ws_size,
                              hipStream_t stream) {
  const float* x  = (const float*)d_in[0];
  const float* wg = (const float*)d_in[1];
  const float* w1 = (const float*)d_in[2];
  const float* b1 = (const float*)d_in[3];
  const float* w2 = (const float*)d_in[4];
  const float* b2 = (const float*)d_in[5];
  float* out = (float*)d_out;

  char* ws = (char*)d_ws;
  int*   ctrl = (int*)ws;                    // [0..7] counts
  int*   tok  = (int*)(ws + 1024);           // 256 KB
  int*   slot = (int*)(ws + 263168);         // 64 KB
  short* xb   = (short*)(ws + 328704);       // 8 MB
  short* w1t  = (short*)(ws + 8717312);      // 8 MB [E][H][D]
  short* w2t  = (short*)(ws + 17105920);     // 8 MB [E][D][H]
  short* hb   = (short*)(ws + 25494528);     // 32 MB
  short* yb   = (short*)(ws + 328704);       // 16 MB, ALIASES xb+w1t (dead by GEMM2)

  float* out_logits = out + (size_t)NTOK * DDIM;
  float* out_idx = out_logits + (size_t)NTOK * NEXP;
  float* out_w = out_idx + (size_t)NTOK * TOPK;

  prep_kernel<<<10240, 256, 0, stream>>>(w1, w1t, w2, w2t, x, wg,
                                         out_logits, out_idx, out_w, xb, ctrl);
  build_lists<<<16, 512, 0, stream>>>(out_idx, ctrl, tok, slot);

  expert_gemm1<<<4096, 256, 0, stream>>>(xb, w1t, b1, hb, ctrl, tok);
  expert_gemm2<<<2048, 256, 0, stream>>>(hb, w2t, b2, yb, ctrl);
  combine_kernel<<<2048, 256, 0, stream>>>(yb, slot, out_w, ctrl, out);
}